// Round 1
// baseline (454.608 us; speedup 1.0000x reference)
//
#include <hip/hip_runtime.h>

#define DSZ 64
#define CCH 16
#define TX 8
#define TY 8
#define TZ 4
#define HX (TX + 2)
#define HY (TY + 2)
#define HZ (TZ + 2)
#define TILE_ELEMS (CCH * HZ * HY * HX)

__global__ __launch_bounds__(256) void nca_fused_kernel(
    const float* __restrict__ x,
    const float* __restrict__ rand_u,
    const float* __restrict__ w1,
    const float* __restrict__ b1,
    const float* __restrict__ w2,
    float* __restrict__ out)
{
    __shared__ float tile[CCH][HZ][HY][HX]; // 16*6*10*10*4 = 38400 B

    const int tid = threadIdx.x;
    const int gx0 = blockIdx.x * TX;
    const int gy0 = blockIdx.y * TY;
    const int zb  = blockIdx.z;
    const int b   = zb >> 4;          // 4 batches
    const int gz0 = (zb & 15) * TZ;   // 16 z-tiles

    const int xbase = b * (CCH * DSZ * DSZ * DSZ);

    // ---- stage x tile (+1 halo, zero padded) into LDS ----
    for (int i = tid; i < TILE_ELEMS; i += 256) {
        int c  = i / (HZ * HY * HX);
        int r  = i - c * (HZ * HY * HX);
        int z  = r / (HY * HX);
        int r2 = r - z * (HY * HX);
        int y  = r2 / HX;
        int xx = r2 - y * HX;
        int gz = gz0 + z - 1;
        int gy = gy0 + y - 1;
        int gx = gx0 + xx - 1;
        float v = 0.0f;
        if ((unsigned)gz < DSZ && (unsigned)gy < DSZ && (unsigned)gx < DSZ)
            v = x[xbase + (c * DSZ + gz) * (DSZ * DSZ) + gy * DSZ + gx];
        ((float*)tile)[i] = v;
    }
    __syncthreads();

    const int tx = tid & 7;
    const int ty = (tid >> 3) & 7;
    const int tz = tid >> 6;

    // ---- perception: ident + 3 sobels per channel, + alive pooling on c==3 ----
    float p[64];
    float pool3 = -1e30f;
    const float gw[3] = {1.0f, 2.0f, 1.0f};
    const float dw[3] = {-1.0f, 0.0f, 1.0f};

    #pragma unroll
    for (int c = 0; c < CCH; ++c) {
        float s1 = 0.0f, s2 = 0.0f, s3 = 0.0f;
        #pragma unroll
        for (int i = 0; i < 3; ++i) {
            #pragma unroll
            for (int j = 0; j < 3; ++j) {
                #pragma unroll
                for (int k = 0; k < 3; ++k) {
                    float v = tile[c][tz + i][ty + j][tx + k];
                    s1 += dw[i] * gw[j] * gw[k] * v;  // d along dim0
                    s2 += gw[i] * dw[j] * gw[k] * v;  // d along dim1
                    s3 += gw[i] * gw[j] * dw[k] * v;  // d along dim2
                    if (c == 3) pool3 = fmaxf(pool3, v);
                }
            }
        }
        p[4 * c + 0] = tile[c][tz + 1][ty + 1][tx + 1];
        p[4 * c + 1] = s1 * 0.125f;
        p[4 * c + 2] = s2 * 0.125f;
        p[4 * c + 3] = s3 * 0.125f;
    }
    const float alive = (pool3 > 0.1f) ? 1.0f : 0.0f;

    const int gz = gz0 + tz, gy = gy0 + ty, gx = gx0 + tx;
    const float ru = rand_u[b * (DSZ * DSZ * DSZ) + gz * (DSZ * DSZ) + gy * DSZ + gx];
    const float smask = (ru <= 0.5f) ? 1.0f : 0.0f;

    // ---- MLP: h = relu(W1 p + b1) [128], upd = W2 h [16] ----
    float upd[16];
    #pragma unroll
    for (int c = 0; c < 16; ++c) upd[c] = 0.0f;

    #pragma unroll 2
    for (int hh = 0; hh < 128; ++hh) {
        float acc = b1[hh];
        #pragma unroll
        for (int pp = 0; pp < 64; ++pp)
            acc = fmaf(w1[hh * 64 + pp], p[pp], acc);
        float r = fmaxf(acc, 0.0f);
        #pragma unroll
        for (int c = 0; c < 16; ++c)
            upd[c] = fmaf(w2[c * 128 + hh], r, upd[c]);
    }

    // ---- write: (x + upd*smask) * alive ----
    #pragma unroll
    for (int c = 0; c < 16; ++c) {
        float xc = p[4 * c]; // ident == center x value
        out[xbase + (c * DSZ + gz) * (DSZ * DSZ) + gy * DSZ + gx] =
            (xc + upd[c] * smask) * alive;
    }
}

extern "C" void kernel_launch(void* const* d_in, const int* in_sizes, int n_in,
                              void* d_out, int out_size, void* d_ws, size_t ws_size,
                              hipStream_t stream)
{
    const float* x      = (const float*)d_in[0];
    const float* rand_u = (const float*)d_in[1];
    const float* w1     = (const float*)d_in[2];
    const float* b1     = (const float*)d_in[3];
    const float* w2     = (const float*)d_in[4];
    float* out = (float*)d_out;

    dim3 grid(DSZ / TX, DSZ / TY, 4 * (DSZ / TZ)); // 8, 8, 64
    dim3 block(256);
    nca_fused_kernel<<<grid, block, 0, stream>>>(x, rand_u, w1, b1, w2, out);
}

// Round 2
// 236.780 us; speedup vs baseline: 1.9200x; 1.9200x over previous
//
#include <hip/hip_runtime.h>

#define HX 12   // padded x-stride (10 used) -> 2-way-free LDS banks
#define HY 10
#define HZ 6
#define CST (HZ*HY*HX)         // 720 floats per channel
#define TILE_ELEMS (16*CST)    // 11520 floats = 46080 B

// LDS map (bytes):
//  [0,46080)      x-tile f32 [16][6][10][12]   -> reused as P bf16 [256][72] (36864 B)
//  [46080,64512)  W1 bf16 [128][72]
//  [64512,68864)  W2 bf16 [16][136]
//  [68864,69888)  alive[256] f32
//  [69888,70912)  msu[256] f32  (smask*alive)

typedef __attribute__((ext_vector_type(8))) short bf16x8;
typedef __attribute__((ext_vector_type(4))) float f32x4;

__device__ __forceinline__ unsigned short f2bf(float f) {
    unsigned u = __builtin_bit_cast(unsigned, f);
    u += 0x7FFFu + ((u >> 16) & 1u);          // RNE
    return (unsigned short)(u >> 16);
}

__global__ __launch_bounds__(256) void nca_fused(
    const float* __restrict__ x, const float* __restrict__ rand_u,
    const float* __restrict__ w1, const float* __restrict__ b1,
    const float* __restrict__ w2, float* __restrict__ out)
{
    __shared__ __align__(16) char smem[70912];
    float*          tile   = (float*)smem;
    unsigned short* W1s    = (unsigned short*)(smem + 46080);
    unsigned short* W2s    = (unsigned short*)(smem + 64512);
    float*          aliveA = (float*)(smem + 68864);
    float*          msuA   = (float*)(smem + 69888);
    unsigned short* Ps     = (unsigned short*)smem;   // after perception

    const int tid = threadIdx.x;
    const int gx0 = blockIdx.x * 8, gy0 = blockIdx.y * 8;
    const int zb  = blockIdx.z;
    const int b   = zb >> 4, gz0 = (zb & 15) * 4;
    const int xbase = b * (16 * 262144);

    // ---- stage x tile (zero halo) + W1/W2 -> bf16 LDS ----
    for (int i = tid; i < TILE_ELEMS; i += 256) {
        int c = i / CST, r = i - c * CST;
        int z = r / (HY * HX), r2 = r - z * (HY * HX);
        int y = r2 / HX, xx = r2 - y * HX;
        int gz = gz0 + z - 1, gy = gy0 + y - 1, gxx = gx0 + xx - 1;
        float v = 0.f;
        if (xx < 10 && (unsigned)gz < 64u && (unsigned)gy < 64u && (unsigned)gxx < 64u)
            v = x[xbase + (c * 64 + gz) * 4096 + gy * 64 + gxx];
        tile[i] = v;
    }
    for (int q = tid; q < 2048; q += 256) {
        float4 v = ((const float4*)w1)[q];
        unsigned short* d = &W1s[(q >> 4) * 72 + (q & 15) * 4];
        d[0] = f2bf(v.x); d[1] = f2bf(v.y); d[2] = f2bf(v.z); d[3] = f2bf(v.w);
    }
    for (int q = tid; q < 512; q += 256) {
        float4 v = ((const float4*)w2)[q];
        unsigned short* d = &W2s[(q >> 5) * 136 + (q & 31) * 4];
        d[0] = f2bf(v.x); d[1] = f2bf(v.y); d[2] = f2bf(v.z); d[3] = f2bf(v.w);
    }
    __syncthreads();

    // ---- perception (fp32 VALU) ----
    const int tx = tid & 7, ty = (tid >> 3) & 7, tz = tid >> 6;
    float p[64];
    float pool3 = -1e30f;
    #pragma unroll
    for (int c = 0; c < 16; ++c) {
        float s1 = 0.f, s2 = 0.f, s3 = 0.f;
        #pragma unroll
        for (int i = 0; i < 3; ++i) {
            const float di = (i == 0) ? -1.f : ((i == 2) ? 1.f : 0.f);
            const float gi = (i == 1) ? 2.f : 1.f;
            #pragma unroll
            for (int j = 0; j < 3; ++j) {
                const float dj = (j == 0) ? -1.f : ((j == 2) ? 1.f : 0.f);
                const float gj = (j == 1) ? 2.f : 1.f;
                #pragma unroll
                for (int k = 0; k < 3; ++k) {
                    const float dk = (k == 0) ? -1.f : ((k == 2) ? 1.f : 0.f);
                    const float gk = (k == 1) ? 2.f : 1.f;
                    float v = tile[((c * HZ + tz + i) * HY + ty + j) * HX + tx + k];
                    s1 = fmaf(di * gj * gk, v, s1);
                    s2 = fmaf(gi * dj * gk, v, s2);
                    s3 = fmaf(gi * gj * dk, v, s3);
                    if (c == 3) pool3 = fmaxf(pool3, v);
                }
            }
        }
        p[4 * c + 0] = tile[((c * HZ + tz + 1) * HY + ty + 1) * HX + tx + 1];
        p[4 * c + 1] = s1 * 0.125f;
        p[4 * c + 2] = s2 * 0.125f;
        p[4 * c + 3] = s3 * 0.125f;
    }
    const float alive = (pool3 > 0.1f) ? 1.f : 0.f;
    const float ru = rand_u[b * 262144 + (gz0 + tz) * 4096 + (gy0 + ty) * 64 + (gx0 + tx)];
    aliveA[tid] = alive;
    msuA[tid]   = (ru <= 0.5f) ? alive : 0.f;
    __syncthreads();   // everyone done READING tile

    // ---- write P (bf16) over the tile region ----
    unsigned pk[32];
    #pragma unroll
    for (int q2 = 0; q2 < 32; ++q2)
        pk[q2] = (unsigned)f2bf(p[2 * q2]) | ((unsigned)f2bf(p[2 * q2 + 1]) << 16);
    uint4* prow = (uint4*)(smem + tid * 144);
    #pragma unroll
    for (int j = 0; j < 8; ++j)
        prow[j] = make_uint4(pk[4 * j], pk[4 * j + 1], pk[4 * j + 2], pk[4 * j + 3]);
    __syncthreads();

    // ---- MFMA phase: h^T = W1p . P^T (GEMM1), upd^T = W2 . h^T (GEMM2) ----
    const int lane = tid & 63, wv = tid >> 6;
    const int g = lane >> 4, r16 = lane & 15;

    // hoist P B-fragments: wave wv owns voxels 64wv..64wv+63 (4 n-tiles)
    bf16x8 pf[4][2];
    #pragma unroll
    for (int n = 0; n < 4; ++n) {
        int v = (4 * wv + n) * 16 + r16;
        #pragma unroll
        for (int ks = 0; ks < 2; ++ks)
            pf[n][ks] = *(const bf16x8*)(Ps + v * 72 + ks * 32 + g * 8);
    }

    f32x4 acc2[4] = {{0,0,0,0},{0,0,0,0},{0,0,0,0},{0,0,0,0}};
    const f32x4 z4 = {0,0,0,0};

    #pragma unroll
    for (int ch = 0; ch < 4; ++ch) {
        // W1 row permutation: tile-pair ch covers hh in [32ch,32ch+32);
        // even tile rows {8g'+0..3}, odd tile rows {8g'+4..7}  (g' = r16>>2)
        const int rE = ch * 32 + 8 * (r16 >> 2) + (r16 & 3);
        const int rO = rE + 4;
        bf16x8 aE0 = *(const bf16x8*)(W1s + rE * 72 + g * 8);
        bf16x8 aE1 = *(const bf16x8*)(W1s + rE * 72 + 32 + g * 8);
        bf16x8 aO0 = *(const bf16x8*)(W1s + rO * 72 + g * 8);
        bf16x8 aO1 = *(const bf16x8*)(W1s + rO * 72 + 32 + g * 8);

        f32x4 accE[4], accO[4];
        #pragma unroll
        for (int n = 0; n < 4; ++n) {
            accE[n] = __builtin_amdgcn_mfma_f32_16x16x32_bf16(aE0, pf[n][0], z4, 0, 0, 0);
            accE[n] = __builtin_amdgcn_mfma_f32_16x16x32_bf16(aE1, pf[n][1], accE[n], 0, 0, 0);
            accO[n] = __builtin_amdgcn_mfma_f32_16x16x32_bf16(aO0, pf[n][0], z4, 0, 0, 0);
            accO[n] = __builtin_amdgcn_mfma_f32_16x16x32_bf16(aO1, pf[n][1], accO[n], 0, 0, 0);
        }

        // bias+relu+pack: lane's acc rows are hh = 32ch + 8g + reg (even) / +4 (odd)
        float4 bE = *(const float4*)(b1 + ch * 32 + 8 * g);
        float4 bO = *(const float4*)(b1 + ch * 32 + 4 + 8 * g);
        bf16x8 w2f = *(const bf16x8*)(W2s + r16 * 136 + ch * 32 + g * 8);
        #pragma unroll
        for (int n = 0; n < 4; ++n) {
            bf16x8 hb;
            hb[0] = (short)f2bf(fmaxf(accE[n][0] + bE.x, 0.f));
            hb[1] = (short)f2bf(fmaxf(accE[n][1] + bE.y, 0.f));
            hb[2] = (short)f2bf(fmaxf(accE[n][2] + bE.z, 0.f));
            hb[3] = (short)f2bf(fmaxf(accE[n][3] + bE.w, 0.f));
            hb[4] = (short)f2bf(fmaxf(accO[n][0] + bO.x, 0.f));
            hb[5] = (short)f2bf(fmaxf(accO[n][1] + bO.y, 0.f));
            hb[6] = (short)f2bf(fmaxf(accO[n][2] + bO.z, 0.f));
            hb[7] = (short)f2bf(fmaxf(accO[n][3] + bO.w, 0.f));
            acc2[n] = __builtin_amdgcn_mfma_f32_16x16x32_bf16(w2f, hb, acc2[n], 0, 0, 0);
        }
    }

    // ---- epilogue: out = x*alive + upd*(smask*alive) ----
    #pragma unroll
    for (int n = 0; n < 4; ++n) {
        int v = (4 * wv + n) * 16 + r16;
        float al = aliveA[v], mu = msuA[v];
        int vx = v & 7, vy = (v >> 3) & 7, vz = v >> 6;
        int gidx = xbase + (gz0 + vz) * 4096 + (gy0 + vy) * 64 + (gx0 + vx);
        #pragma unroll
        for (int reg = 0; reg < 4; ++reg) {
            int c = 4 * g + reg;
            int idx = gidx + c * 262144;
            out[idx] = x[idx] * al + acc2[n][reg] * mu;
        }
    }
}

extern "C" void kernel_launch(void* const* d_in, const int* in_sizes, int n_in,
                              void* d_out, int out_size, void* d_ws, size_t ws_size,
                              hipStream_t stream)
{
    const float* x      = (const float*)d_in[0];
    const float* rand_u = (const float*)d_in[1];
    const float* w1     = (const float*)d_in[2];
    const float* b1     = (const float*)d_in[3];
    const float* w2     = (const float*)d_in[4];
    float* out = (float*)d_out;

    dim3 grid(8, 8, 64);
    dim3 block(256);
    nca_fused<<<grid, block, 0, stream>>>(x, rand_u, w1, b1, w2, out);
}